// Round 4
// baseline (1678.406 us; speedup 1.0000x reference)
//
#include <hip/hip_runtime.h>

// GraphAttention: N=12288, IN=OUT=128.
// e_new = emb@W.T ; s = e_new@a1 ; t = e_new@a2
// e[i][j] = leaky(s_i + t_j) masked by adj; softmax rows; out = relu(att @ e_new)
//
//  k1: bf16 MFMA gemm emb@W.T -> Vt (bf16, transposed [d][j]), s[], t[] (fp32)
//      + Tmax via biased-float atomicMax (t+64>0 so int compare is monotone).
//  k2: streaming masked-softmax-PV. adj + Vt staged through LDS with coalesced
//      global loads (scattered A-fragment loads saturate the request pipe —
//      measured r1/r2). TWO-deep register prefetch so commit's vmcnt wait is
//      ~0 (HBM latency ~900cyc covered by 2 compute phases). 1 barrier/chunk.
//      8 col-splits, partials to ws (no atomics).
//  k3: out = relu( (sum of partials) * (1/sum of l partials) )  [kl merged in]

#define NN 12288
#define DIM 128
#define CSPLIT 8
#define COLS_PER (NN / CSPLIT)   // 1536
#define BK 32
#define NCHUNK (COLS_PER / BK)   // 48

typedef __bf16 bf16x8 __attribute__((ext_vector_type(8)));
typedef float f32x4 __attribute__((ext_vector_type(4)));

// ---------------- kernel 1: e_new = emb @ W.T (bf16 MFMA), emits Vt, s, t ----
__global__ __launch_bounds__(64) void k1_gemm(const float* __restrict__ emb,
                                              const float* __restrict__ W,
                                              const float* __restrict__ a,
                                              __bf16* __restrict__ Vt,
                                              float* __restrict__ s,
                                              float* __restrict__ t,
                                              unsigned* __restrict__ tmax) {
  const int lane = threadIdx.x;
  const int m = lane & 15;
  const int quad = lane >> 4;
  const int row0 = blockIdx.x * 16;  // this wave: 16 rows

  f32x4 acc[8];
#pragma unroll
  for (int nb = 0; nb < 8; nb++) acc[nb] = (f32x4){0.f, 0.f, 0.f, 0.f};

#pragma unroll
  for (int ks = 0; ks < 4; ks++) {
    const int k0 = ks * 32 + quad * 8;
    const float* ep = emb + (size_t)(row0 + m) * DIM + k0;
    float4 lo = *(const float4*)ep;
    float4 hi = *(const float4*)(ep + 4);
    bf16x8 af = {(__bf16)lo.x, (__bf16)lo.y, (__bf16)lo.z, (__bf16)lo.w,
                 (__bf16)hi.x, (__bf16)hi.y, (__bf16)hi.z, (__bf16)hi.w};
#pragma unroll
    for (int nb = 0; nb < 8; nb++) {
      const float* wp = W + (size_t)(nb * 16 + m) * DIM + k0;
      float4 wlo = *(const float4*)wp;
      float4 whi = *(const float4*)(wp + 4);
      bf16x8 bf = {(__bf16)wlo.x, (__bf16)wlo.y, (__bf16)wlo.z, (__bf16)wlo.w,
                   (__bf16)whi.x, (__bf16)whi.y, (__bf16)whi.z, (__bf16)whi.w};
      acc[nb] = __builtin_amdgcn_mfma_f32_16x16x32_bf16(af, bf, acc[nb], 0, 0, 0);
    }
  }

  float a1v[8], a2v[8];
#pragma unroll
  for (int nb = 0; nb < 8; nb++) {
    a1v[nb] = a[nb * 16 + m];
    a2v[nb] = a[DIM + nb * 16 + m];
  }
  float tm_local = 0.f;  // biased-key max (biased t is ~[60,68] > 0)
  // C/D layout: row = quad*4 + r, col = nb*16 + m
#pragma unroll
  for (int r = 0; r < 4; r++) {
    const int gr = row0 + quad * 4 + r;
    float ps = 0.f, pt = 0.f;
#pragma unroll
    for (int nb = 0; nb < 8; nb++) {
      float e = acc[nb][r];
      ps += e * a1v[nb];
      pt += e * a2v[nb];
      Vt[(size_t)(nb * 16 + m) * NN + gr] = (__bf16)e;
    }
    ps += __shfl_xor(ps, 1); ps += __shfl_xor(ps, 2);
    ps += __shfl_xor(ps, 4); ps += __shfl_xor(ps, 8);
    pt += __shfl_xor(pt, 1); pt += __shfl_xor(pt, 2);
    pt += __shfl_xor(pt, 4); pt += __shfl_xor(pt, 8);
    if (m == 0) {
      s[gr] = ps;
      t[gr] = pt;
      tm_local = fmaxf(tm_local, pt + 64.0f);
    }
  }
  if (m == 0) atomicMax(tmax, __float_as_uint(tm_local));
}

// ---------------- kernel 2: masked softmax + PV, LDS-staged -----------------
__global__ __launch_bounds__(256, 3) void k2_attn(const int* __restrict__ adj,
                                                  const __bf16* __restrict__ Vt,
                                                  const float* __restrict__ s,
                                                  const float* __restrict__ t,
                                                  const unsigned* __restrict__ tmaxp,
                                                  float* __restrict__ part,
                                                  float* __restrict__ lpart) {
  // adj tile: 128 rows x 32 cols, 1 byte/elem, row stride 40 B (5 ulongs)
  __shared__ unsigned long long adjb[2][128][5];
  // Vt tile: 128 dims x 32 cols bf16, row stride 80 B (16B-aligned)
  __shared__ __attribute__((aligned(16))) __bf16 vtb[2][128][40];

  const int tid = threadIdx.x;
  const int lane = tid & 63;
  const int wave = tid >> 6;
  const int m = lane & 15;
  const int quad = lane >> 4;
  const int row0 = blockIdx.x * 128;
  const int cs = blockIdx.y;
  const int col0 = cs * COLS_PER;
  const int rowA = row0 + wave * 32 + m;
  const int rowB = rowA + 16;

  const float Tmax = __uint_as_float(*tmaxp) - 64.0f;
  const float sA = s[rowA], sB = s[rowB];
  const float uA = sA + Tmax, uB = sB + Tmax;
  const float mA = fmaxf(uA, 0.01f * uA);  // per-row fixed softmax shift (upper bound)
  const float mB = fmaxf(uB, 0.01f * uB);

  f32x4 accA[8], accB[8];
#pragma unroll
  for (int nb = 0; nb < 8; nb++) {
    accA[nb] = (f32x4){0.f, 0.f, 0.f, 0.f};
    accB[nb] = (f32x4){0.f, 0.f, 0.f, 0.f};
  }
  float lA = 0.f, lB = 0.f;

  // 2-deep staging registers (global -> reg -> LDS)
  int4 ga[2][4];
  bf16x8 gv[2][2];
  float4 gt[2][2];
  const int fr = tid >> 3, fc = (tid & 7) * 4;  // adj: 8 rows x 128 B per inst
  const int vd = tid >> 2, vc = (tid & 3) * 8;  // Vt: 16 rows x 64 B per inst
  const float* tp0 = t + col0 + quad * 8;

  auto fetch = [&](int c, int b) {
    const int cc = col0 + c * BK;
#pragma unroll
    for (int p = 0; p < 4; p++)
      ga[b][p] = *(const int4*)(adj + (size_t)(row0 + fr + p * 32) * NN + cc + fc);
#pragma unroll
    for (int p = 0; p < 2; p++)
      gv[b][p] = *(const bf16x8*)(Vt + (size_t)(vd + p * 64) * NN + cc + vc);
    gt[b][0] = *(const float4*)(tp0 + c * BK);
    gt[b][1] = *(const float4*)(tp0 + c * BK + 4);
  };
  auto commit = [&](int c, int b) {  // LDS buf c&1 <- reg set b
    const int lb = c & 1;
#pragma unroll
    for (int p = 0; p < 4; p++) {
      unsigned pk = (unsigned)(ga[b][p].x != 0) | ((unsigned)(ga[b][p].y != 0) << 8) |
                    ((unsigned)(ga[b][p].z != 0) << 16) | ((unsigned)(ga[b][p].w != 0) << 24);
      *(unsigned*)((unsigned char*)&adjb[lb][fr + p * 32][0] + fc) = pk;
    }
#pragma unroll
    for (int p = 0; p < 2; p++)
      *(bf16x8*)&vtb[lb][vd + p * 64][vc] = gv[b][p];
  };

  fetch(0, 0);
  commit(0, 0);
  fetch(1, 1);
  __syncthreads();

  for (int c = 0; c < NCHUNK; c++) {
    const int cur = c & 1;
    // read chunk-c t out of reg set `cur` before overwriting it with fetch(c+2)
    float4 ct0 = gt[cur][0];
    float4 ct1 = gt[cur][1];
    if (c + 2 < NCHUNK) fetch(c + 2, cur);

    // ---- compute on LDS buffer cur ----
    unsigned long long avA = adjb[cur][wave * 32 + m][quad];
    unsigned long long avB = adjb[cur][wave * 32 + 16 + m][quad];

    bf16x8 pA, pB;
#define PEL(frag, jj, tv, av, ss, mm, ll)                               \
    {                                                                   \
      float v = (ss) + (tv);                                            \
      float lv = fmaxf(v, 0.01f * v);                                   \
      float e = (((av) >> (8 * (jj))) & 1) ? __expf(lv - (mm)) : 0.f;   \
      (ll) += e;                                                        \
      frag[jj] = (__bf16)e;                                             \
    }
    PEL(pA, 0, ct0.x, avA, sA, mA, lA)
    PEL(pA, 1, ct0.y, avA, sA, mA, lA)
    PEL(pA, 2, ct0.z, avA, sA, mA, lA)
    PEL(pA, 3, ct0.w, avA, sA, mA, lA)
    PEL(pA, 4, ct1.x, avA, sA, mA, lA)
    PEL(pA, 5, ct1.y, avA, sA, mA, lA)
    PEL(pA, 6, ct1.z, avA, sA, mA, lA)
    PEL(pA, 7, ct1.w, avA, sA, mA, lA)
    PEL(pB, 0, ct0.x, avB, sB, mB, lB)
    PEL(pB, 1, ct0.y, avB, sB, mB, lB)
    PEL(pB, 2, ct0.z, avB, sB, mB, lB)
    PEL(pB, 3, ct0.w, avB, sB, mB, lB)
    PEL(pB, 4, ct1.x, avB, sB, mB, lB)
    PEL(pB, 5, ct1.y, avB, sB, mB, lB)
    PEL(pB, 6, ct1.z, avB, sB, mB, lB)
    PEL(pB, 7, ct1.w, avB, sB, mB, lB)
#undef PEL

#pragma unroll
    for (int nb = 0; nb < 8; nb++) {
      bf16x8 bv = *(const bf16x8*)&vtb[cur][nb * 16 + m][quad * 8];
      accA[nb] = __builtin_amdgcn_mfma_f32_16x16x32_bf16(pA, bv, accA[nb], 0, 0, 0);
      accB[nb] = __builtin_amdgcn_mfma_f32_16x16x32_bf16(pB, bv, accB[nb], 0, 0, 0);
    }

    // commit chunk c+1 (its loads were issued at iter c-1: ~2 phases of slack)
    if (c + 1 < NCHUNK) {
      commit(c + 1, (c + 1) & 1);
      __syncthreads();
    }
  }

  // row-sum partials: lanes {m, m+16, m+32, m+48} hold same row
  lA += __shfl_xor(lA, 16); lA += __shfl_xor(lA, 32);
  lB += __shfl_xor(lB, 16); lB += __shfl_xor(lB, 32);
  if (quad == 0) {
    lpart[(size_t)cs * NN + rowA] = lA;
    lpart[(size_t)cs * NN + rowB] = lB;
  }

  // C/D layout: row = quad*4 + r, col = nb*16 + m. Plain stores to partial slice.
  float* po = part + ((size_t)cs * NN + row0 + wave * 32) * DIM;
#pragma unroll
  for (int nb = 0; nb < 8; nb++) {
#pragma unroll
    for (int r = 0; r < 4; r++) {
      po[(size_t)(quad * 4 + r) * DIM + nb * 16 + m] = accA[nb][r];
      po[(size_t)(16 + quad * 4 + r) * DIM + nb * 16 + m] = accB[nb][r];
    }
  }
}

// ---------------- kernel 3: reduce partials + normalize + relu ---------------
__global__ __launch_bounds__(256) void k3_fin(const float* __restrict__ part,
                                              const float* __restrict__ lpart,
                                              float* __restrict__ out) {
  __shared__ float linv_s[8];
  const int r0 = blockIdx.x * 8;  // 8 rows per block, 1536 blocks
  if (threadIdx.x < 8) {
    float l = 0.f;
#pragma unroll
    for (int cs = 0; cs < CSPLIT; cs++) l += lpart[(size_t)cs * NN + r0 + threadIdx.x];
    linv_s[threadIdx.x] = 1.0f / l;
  }
  __syncthreads();
  const int idx = blockIdx.x * 256 + threadIdx.x;  // float4 index over NN*DIM/4
  const float4* p4 = (const float4*)part;
  float4 acc = p4[idx];
#pragma unroll
  for (int cs = 1; cs < CSPLIT; cs++) {
    float4 v = p4[(size_t)cs * (NN * DIM / 4) + idx];
    acc.x += v.x; acc.y += v.y; acc.z += v.z; acc.w += v.w;
  }
  const float li = linv_s[threadIdx.x >> 5];
  float4 o;
  o.x = fmaxf(acc.x * li, 0.f);
  o.y = fmaxf(acc.y * li, 0.f);
  o.z = fmaxf(acc.z * li, 0.f);
  o.w = fmaxf(acc.w * li, 0.f);
  ((float4*)out)[idx] = o;
}

extern "C" void kernel_launch(void* const* d_in, const int* in_sizes, int n_in,
                              void* d_out, int out_size, void* d_ws, size_t ws_size,
                              hipStream_t stream) {
  (void)in_sizes; (void)n_in; (void)out_size; (void)ws_size;
  const float* emb = (const float*)d_in[0];
  const int* adj = (const int*)d_in[1];
  const float* W = (const float*)d_in[2];
  const float* a = (const float*)d_in[3];
  float* out = (float*)d_out;

  char* ws = (char*)d_ws;
  __bf16* Vt = (__bf16*)ws;                       // 3,145,728 B
  float* s = (float*)(ws + 3145728);              // 49,152 B
  float* t = (float*)(ws + 3194880);              // 49,152 B
  float* lpart = (float*)(ws + 3244032);          // 8*12288*4 = 393,216 B
  unsigned* tmax = (unsigned*)(ws + 3637248);     // 256 B
  float* part = (float*)(ws + 3637504);           // 8*12288*128*4 = 50,331,648 B

  hipMemsetAsync(tmax, 0, 4, stream);
  k1_gemm<<<NN / 16, 64, 0, stream>>>(emb, W, a, Vt, s, t, tmax);
  dim3 g2(NN / 128, CSPLIT);
  k2_attn<<<g2, 256, 0, stream>>>(adj, Vt, s, t, tmax, part, lpart);
  k3_fin<<<NN / 8, 256, 0, stream>>>(part, lpart, out);
}

// Round 5
// 996.431 us; speedup vs baseline: 1.6844x; 1.6844x over previous
//
#include <hip/hip_runtime.h>

// GraphAttention: N=12288, IN=OUT=128.
// e_new = emb@W.T ; s = e_new@a1 ; t = e_new@a2
// e[i][j] = leaky(s_i + t_j) masked by adj; softmax rows; out = relu(att @ e_new)
//
//  k1: bf16 MFMA gemm emb@W.T -> Vt (bf16, transposed [d][j]), s[], t[] (fp32)
//      + Tmax via biased-float atomicMax (t+64>0 so int compare is monotone).
//  k2: streaming masked-softmax-PV. adj + Vt staged through LDS with coalesced
//      global loads (scattered A-fragment loads saturate the request pipe —
//      measured r1/r2). TWO-deep register prefetch with NAMED register sets
//      and a manually x2-unrolled chunk loop — round 4 proved that
//      runtime-indexed local arrays get demoted to scratch (902 MB of spill
//      writes). 1 barrier/chunk. 8 col-splits, partials to ws (no atomics).
//  k3: out = relu( (sum of partials) * (1/sum of l partials) )

#define NN 12288
#define DIM 128
#define CSPLIT 8
#define COLS_PER (NN / CSPLIT)   // 1536
#define BK 32
#define NCHUNK (COLS_PER / BK)   // 48 (even — required by the x2 unroll)

typedef __bf16 bf16x8 __attribute__((ext_vector_type(8)));
typedef float f32x4 __attribute__((ext_vector_type(4)));

// ---------------- kernel 1: e_new = emb @ W.T (bf16 MFMA), emits Vt, s, t ----
__global__ __launch_bounds__(64) void k1_gemm(const float* __restrict__ emb,
                                              const float* __restrict__ W,
                                              const float* __restrict__ a,
                                              __bf16* __restrict__ Vt,
                                              float* __restrict__ s,
                                              float* __restrict__ t,
                                              unsigned* __restrict__ tmax) {
  const int lane = threadIdx.x;
  const int m = lane & 15;
  const int quad = lane >> 4;
  const int row0 = blockIdx.x * 16;  // this wave: 16 rows

  f32x4 acc[8];
#pragma unroll
  for (int nb = 0; nb < 8; nb++) acc[nb] = (f32x4){0.f, 0.f, 0.f, 0.f};

#pragma unroll
  for (int ks = 0; ks < 4; ks++) {
    const int k0 = ks * 32 + quad * 8;
    const float* ep = emb + (size_t)(row0 + m) * DIM + k0;
    float4 lo = *(const float4*)ep;
    float4 hi = *(const float4*)(ep + 4);
    bf16x8 af = {(__bf16)lo.x, (__bf16)lo.y, (__bf16)lo.z, (__bf16)lo.w,
                 (__bf16)hi.x, (__bf16)hi.y, (__bf16)hi.z, (__bf16)hi.w};
#pragma unroll
    for (int nb = 0; nb < 8; nb++) {
      const float* wp = W + (size_t)(nb * 16 + m) * DIM + k0;
      float4 wlo = *(const float4*)wp;
      float4 whi = *(const float4*)(wp + 4);
      bf16x8 bf = {(__bf16)wlo.x, (__bf16)wlo.y, (__bf16)wlo.z, (__bf16)wlo.w,
                   (__bf16)whi.x, (__bf16)whi.y, (__bf16)whi.z, (__bf16)whi.w};
      acc[nb] = __builtin_amdgcn_mfma_f32_16x16x32_bf16(af, bf, acc[nb], 0, 0, 0);
    }
  }

  float a1v[8], a2v[8];
#pragma unroll
  for (int nb = 0; nb < 8; nb++) {
    a1v[nb] = a[nb * 16 + m];
    a2v[nb] = a[DIM + nb * 16 + m];
  }
  float tm_local = 0.f;  // biased-key max (biased t is ~[60,68] > 0)
  // C/D layout: row = quad*4 + r, col = nb*16 + m
#pragma unroll
  for (int r = 0; r < 4; r++) {
    const int gr = row0 + quad * 4 + r;
    float ps = 0.f, pt = 0.f;
#pragma unroll
    for (int nb = 0; nb < 8; nb++) {
      float e = acc[nb][r];
      ps += e * a1v[nb];
      pt += e * a2v[nb];
      Vt[(size_t)(nb * 16 + m) * NN + gr] = (__bf16)e;
    }
    ps += __shfl_xor(ps, 1); ps += __shfl_xor(ps, 2);
    ps += __shfl_xor(ps, 4); ps += __shfl_xor(ps, 8);
    pt += __shfl_xor(pt, 1); pt += __shfl_xor(pt, 2);
    pt += __shfl_xor(pt, 4); pt += __shfl_xor(pt, 8);
    if (m == 0) {
      s[gr] = ps;
      t[gr] = pt;
      tm_local = fmaxf(tm_local, pt + 64.0f);
    }
  }
  if (m == 0) atomicMax(tmax, __float_as_uint(tm_local));
}

// ---------------- kernel 2: masked softmax + PV, LDS-staged, 2-deep pipe ----
__global__ __launch_bounds__(256, 3) void k2_attn(const int* __restrict__ adj,
                                                  const __bf16* __restrict__ Vt,
                                                  const float* __restrict__ s,
                                                  const float* __restrict__ t,
                                                  const unsigned* __restrict__ tmaxp,
                                                  float* __restrict__ part,
                                                  float* __restrict__ lpart) {
  // adj tile: 128 rows x 32 cols, 1 byte/elem, row stride 40 B (5 ulongs)
  __shared__ unsigned long long adjb[2][128][5];
  // Vt tile: 128 dims x 32 cols bf16, row stride 80 B (16B-aligned)
  __shared__ __attribute__((aligned(16))) __bf16 vtb[2][128][40];

  const int tid = threadIdx.x;
  const int lane = tid & 63;
  const int wave = tid >> 6;
  const int m = lane & 15;
  const int quad = lane >> 4;
  const int row0 = blockIdx.x * 128;
  const int cs = blockIdx.y;
  const int col0 = cs * COLS_PER;
  const int rowA = row0 + wave * 32 + m;
  const int rowB = rowA + 16;

  const float Tmax = __uint_as_float(*tmaxp) - 64.0f;
  const float sA = s[rowA], sB = s[rowB];
  const float uA = sA + Tmax, uB = sB + Tmax;
  const float mA = fmaxf(uA, 0.01f * uA);  // per-row fixed softmax shift (upper bound)
  const float mB = fmaxf(uB, 0.01f * uB);

  f32x4 accA[8], accB[8];
#pragma unroll
  for (int nb = 0; nb < 8; nb++) {
    accA[nb] = (f32x4){0.f, 0.f, 0.f, 0.f};
    accB[nb] = (f32x4){0.f, 0.f, 0.f, 0.f};
  }
  float lA = 0.f, lB = 0.f;

  // 2-deep staging: NAMED register sets (never runtime-indexed!)
  int4 ga0[4], ga1[4];
  bf16x8 gv0[2], gv1[2];
  float4 gt0a, gt0b, gt1a, gt1b;
  const int fr = tid >> 3, fc = (tid & 7) * 4;  // adj: 8 rows x 128 B per inst
  const int vd = tid >> 2, vc = (tid & 3) * 8;  // Vt: 16 rows x 64 B per inst
  const float* tp0 = t + col0 + quad * 8;

  auto fetch0 = [&](int c) {
    const int cc = col0 + c * BK;
#pragma unroll
    for (int p = 0; p < 4; p++)
      ga0[p] = *(const int4*)(adj + (size_t)(row0 + fr + p * 32) * NN + cc + fc);
#pragma unroll
    for (int p = 0; p < 2; p++)
      gv0[p] = *(const bf16x8*)(Vt + (size_t)(vd + p * 64) * NN + cc + vc);
    gt0a = *(const float4*)(tp0 + c * BK);
    gt0b = *(const float4*)(tp0 + c * BK + 4);
  };
  auto fetch1 = [&](int c) {
    const int cc = col0 + c * BK;
#pragma unroll
    for (int p = 0; p < 4; p++)
      ga1[p] = *(const int4*)(adj + (size_t)(row0 + fr + p * 32) * NN + cc + fc);
#pragma unroll
    for (int p = 0; p < 2; p++)
      gv1[p] = *(const bf16x8*)(Vt + (size_t)(vd + p * 64) * NN + cc + vc);
    gt1a = *(const float4*)(tp0 + c * BK);
    gt1b = *(const float4*)(tp0 + c * BK + 4);
  };
  auto commit0 = [&]() {  // set0 -> LDS buf 0
#pragma unroll
    for (int p = 0; p < 4; p++) {
      unsigned pk = (unsigned)(ga0[p].x != 0) | ((unsigned)(ga0[p].y != 0) << 8) |
                    ((unsigned)(ga0[p].z != 0) << 16) | ((unsigned)(ga0[p].w != 0) << 24);
      *(unsigned*)((unsigned char*)&adjb[0][fr + p * 32][0] + fc) = pk;
    }
#pragma unroll
    for (int p = 0; p < 2; p++)
      *(bf16x8*)&vtb[0][vd + p * 64][vc] = gv0[p];
  };
  auto commit1 = [&]() {  // set1 -> LDS buf 1
#pragma unroll
    for (int p = 0; p < 4; p++) {
      unsigned pk = (unsigned)(ga1[p].x != 0) | ((unsigned)(ga1[p].y != 0) << 8) |
                    ((unsigned)(ga1[p].z != 0) << 16) | ((unsigned)(ga1[p].w != 0) << 24);
      *(unsigned*)((unsigned char*)&adjb[1][fr + p * 32][0] + fc) = pk;
    }
#pragma unroll
    for (int p = 0; p < 2; p++)
      *(bf16x8*)&vtb[1][vd + p * 64][vc] = gv1[p];
  };

  auto compute = [&](int lb, float4 ct0, float4 ct1) {
    unsigned long long avA = adjb[lb][wave * 32 + m][quad];
    unsigned long long avB = adjb[lb][wave * 32 + 16 + m][quad];
    bf16x8 pA, pB;
#define PEL(frag, jj, tv, av, ss, mm, ll)                               \
    {                                                                   \
      float v = (ss) + (tv);                                            \
      float lv = fmaxf(v, 0.01f * v);                                   \
      float e = (((av) >> (8 * (jj))) & 1) ? __expf(lv - (mm)) : 0.f;   \
      (ll) += e;                                                        \
      frag[jj] = (__bf16)e;                                             \
    }
    PEL(pA, 0, ct0.x, avA, sA, mA, lA)
    PEL(pA, 1, ct0.y, avA, sA, mA, lA)
    PEL(pA, 2, ct0.z, avA, sA, mA, lA)
    PEL(pA, 3, ct0.w, avA, sA, mA, lA)
    PEL(pA, 4, ct1.x, avA, sA, mA, lA)
    PEL(pA, 5, ct1.y, avA, sA, mA, lA)
    PEL(pA, 6, ct1.z, avA, sA, mA, lA)
    PEL(pA, 7, ct1.w, avA, sA, mA, lA)
    PEL(pB, 0, ct0.x, avB, sB, mB, lB)
    PEL(pB, 1, ct0.y, avB, sB, mB, lB)
    PEL(pB, 2, ct0.z, avB, sB, mB, lB)
    PEL(pB, 3, ct0.w, avB, sB, mB, lB)
    PEL(pB, 4, ct1.x, avB, sB, mB, lB)
    PEL(pB, 5, ct1.y, avB, sB, mB, lB)
    PEL(pB, 6, ct1.z, avB, sB, mB, lB)
    PEL(pB, 7, ct1.w, avB, sB, mB, lB)
#undef PEL
#pragma unroll
    for (int nb = 0; nb < 8; nb++) {
      bf16x8 bv = *(const bf16x8*)&vtb[lb][nb * 16 + m][quad * 8];
      accA[nb] = __builtin_amdgcn_mfma_f32_16x16x32_bf16(pA, bv, accA[nb], 0, 0, 0);
      accB[nb] = __builtin_amdgcn_mfma_f32_16x16x32_bf16(pB, bv, accB[nb], 0, 0, 0);
    }
  };

  fetch0(0);
  commit0();
  fetch1(1);
  __syncthreads();

  for (int c = 0; c < NCHUNK; c += 2) {
    // ---- chunk c: LDS buf 0, reg set 0 ----
    {
      float4 ct0 = gt0a, ct1 = gt0b;         // save before overwriting set 0
      if (c + 2 < NCHUNK) fetch0(c + 2);     // issued ~2 compute phases early
      compute(0, ct0, ct1);
      commit1();                             // chunk c+1 -> buf 1 (loads from iter c-1)
      __syncthreads();
    }
    // ---- chunk c+1: LDS buf 1, reg set 1 ----
    {
      float4 ct0 = gt1a, ct1 = gt1b;
      if (c + 3 < NCHUNK) fetch1(c + 3);
      compute(1, ct0, ct1);
      if (c + 2 < NCHUNK) {
        commit0();                           // chunk c+2 -> buf 0
        __syncthreads();
      }
    }
  }

  // row-sum partials: lanes {m, m+16, m+32, m+48} hold same row
  lA += __shfl_xor(lA, 16); lA += __shfl_xor(lA, 32);
  lB += __shfl_xor(lB, 16); lB += __shfl_xor(lB, 32);
  if (quad == 0) {
    lpart[(size_t)cs * NN + rowA] = lA;
    lpart[(size_t)cs * NN + rowB] = lB;
  }

  // C/D layout: row = quad*4 + r, col = nb*16 + m. Plain stores to partial slice.
  float* po = part + ((size_t)cs * NN + row0 + wave * 32) * DIM;
#pragma unroll
  for (int nb = 0; nb < 8; nb++) {
#pragma unroll
    for (int r = 0; r < 4; r++) {
      po[(size_t)(quad * 4 + r) * DIM + nb * 16 + m] = accA[nb][r];
      po[(size_t)(16 + quad * 4 + r) * DIM + nb * 16 + m] = accB[nb][r];
    }
  }
}

// ---------------- kernel 3: reduce partials + normalize + relu ---------------
__global__ __launch_bounds__(256) void k3_fin(const float* __restrict__ part,
                                              const float* __restrict__ lpart,
                                              float* __restrict__ out) {
  __shared__ float linv_s[8];
  const int r0 = blockIdx.x * 8;  // 8 rows per block, 1536 blocks
  if (threadIdx.x < 8) {
    float l = 0.f;
#pragma unroll
    for (int cs = 0; cs < CSPLIT; cs++) l += lpart[(size_t)cs * NN + r0 + threadIdx.x];
    linv_s[threadIdx.x] = 1.0f / l;
  }
  __syncthreads();
  const int idx = blockIdx.x * 256 + threadIdx.x;  // float4 index over NN*DIM/4
  const float4* p4 = (const float4*)part;
  float4 acc = p4[idx];
#pragma unroll
  for (int cs = 1; cs < CSPLIT; cs++) {
    float4 v = p4[(size_t)cs * (NN * DIM / 4) + idx];
    acc.x += v.x; acc.y += v.y; acc.z += v.z; acc.w += v.w;
  }
  const float li = linv_s[threadIdx.x >> 5];
  float4 o;
  o.x = fmaxf(acc.x * li, 0.f);
  o.y = fmaxf(acc.y * li, 0.f);
  o.z = fmaxf(acc.z * li, 0.f);
  o.w = fmaxf(acc.w * li, 0.f);
  ((float4*)out)[idx] = o;
}

extern "C" void kernel_launch(void* const* d_in, const int* in_sizes, int n_in,
                              void* d_out, int out_size, void* d_ws, size_t ws_size,
                              hipStream_t stream) {
  (void)in_sizes; (void)n_in; (void)out_size; (void)ws_size;
  const float* emb = (const float*)d_in[0];
  const int* adj = (const int*)d_in[1];
  const float* W = (const float*)d_in[2];
  const float* a = (const float*)d_in[3];
  float* out = (float*)d_out;

  char* ws = (char*)d_ws;
  __bf16* Vt = (__bf16*)ws;                       // 3,145,728 B
  float* s = (float*)(ws + 3145728);              // 49,152 B
  float* t = (float*)(ws + 3194880);              // 49,152 B
  float* lpart = (float*)(ws + 3244032);          // 8*12288*4 = 393,216 B
  unsigned* tmax = (unsigned*)(ws + 3637248);     // 256 B
  float* part = (float*)(ws + 3637504);           // 8*12288*128*4 = 50,331,648 B

  hipMemsetAsync(tmax, 0, 4, stream);
  k1_gemm<<<NN / 16, 64, 0, stream>>>(emb, W, a, Vt, s, t, tmax);
  dim3 g2(NN / 128, CSPLIT);
  k2_attn<<<g2, 256, 0, stream>>>(adj, Vt, s, t, tmax, part, lpart);
  k3_fin<<<NN / 8, 256, 0, stream>>>(part, lpart, out);
}

// Round 7
// 839.578 us; speedup vs baseline: 1.9991x; 1.1868x over previous
//
#include <hip/hip_runtime.h>

// GraphAttention: N=12288, IN=OUT=128.
// e_new = emb@W.T ; s = e_new@a1 ; t = e_new@a2
// e[i][j] = leaky(s_i + t_j) masked by adj; softmax rows; out = relu(att @ e_new)
//
//  k1: bf16 MFMA gemm emb@W.T -> Vtb (bf16, WAVE-FRAGMENT layout: exactly the
//      bytes k2's B-fragment load needs, 16 B/lane coalesced), s[], t[] (fp32)
//      + Tmax via biased-float atomicMax. (Relayout hand-verified r6 post-mortem.)
//  k2: streaming masked-softmax-PV, ZERO barriers, ZERO LDS memory. The adj
//      coalesced->fragment transpose is done with __shfl (ds_bpermute register
//      crossbar) — r6 failed because LDS staging written as u32 / read as u64
//      has no TBAA dependency once __syncthreads is gone, so reads were not
//      ordered after writes. Register path has no such hazard. adj prefetched
//      1 chunk deep in NAMED register sets (r4: runtime-indexed = scratch).
//  k3: out = relu( (sum of partials) * (1/sum of l partials) )

#define NN 12288
#define DIM 128
#define CSPLIT 8
#define COLS_PER (NN / CSPLIT)   // 1536
#define BK 32
#define NCHUNK (COLS_PER / BK)   // 48 (even — required by the x2 unroll)

typedef __bf16 bf16x8 __attribute__((ext_vector_type(8)));
typedef __bf16 bf16x4 __attribute__((ext_vector_type(4)));
typedef float f32x4 __attribute__((ext_vector_type(4)));

// ---------------- kernel 1: e_new = emb @ W.T -> Vtb fragments, s, t --------
__global__ __launch_bounds__(64) void k1_gemm(const float* __restrict__ emb,
                                              const float* __restrict__ W,
                                              const float* __restrict__ a,
                                              __bf16* __restrict__ Vtb,
                                              float* __restrict__ s,
                                              float* __restrict__ t,
                                              unsigned* __restrict__ tmax) {
  const int lane = threadIdx.x;
  const int m = lane & 15;
  const int quad = lane >> 4;
  const int row0 = blockIdx.x * 16;  // this wave: 16 rows of e_new

  f32x4 acc[8];
#pragma unroll
  for (int nb = 0; nb < 8; nb++) acc[nb] = (f32x4){0.f, 0.f, 0.f, 0.f};

#pragma unroll
  for (int ks = 0; ks < 4; ks++) {
    const int k0 = ks * 32 + quad * 8;
    const float* ep = emb + (size_t)(row0 + m) * DIM + k0;
    float4 lo = *(const float4*)ep;
    float4 hi = *(const float4*)(ep + 4);
    bf16x8 af = {(__bf16)lo.x, (__bf16)lo.y, (__bf16)lo.z, (__bf16)lo.w,
                 (__bf16)hi.x, (__bf16)hi.y, (__bf16)hi.z, (__bf16)hi.w};
#pragma unroll
    for (int nb = 0; nb < 8; nb++) {
      const float* wp = W + (size_t)(nb * 16 + m) * DIM + k0;
      float4 wlo = *(const float4*)wp;
      float4 whi = *(const float4*)(wp + 4);
      bf16x8 bf = {(__bf16)wlo.x, (__bf16)wlo.y, (__bf16)wlo.z, (__bf16)wlo.w,
                   (__bf16)whi.x, (__bf16)whi.y, (__bf16)whi.z, (__bf16)whi.w};
      acc[nb] = __builtin_amdgcn_mfma_f32_16x16x32_bf16(af, bf, acc[nb], 0, 0, 0);
    }
  }

  // ---- Vtb fragment store ----
  // Reader (k2): bv[nb][j] at chunk K, lane'=(quad',m') must be
  //   e_new[K*32 + quad'*8 + j][nb*16 + m']   at (K*8+nb)*512 + lane'*8 + j.
  // Writer holds e_new[gr][nb*16+m], gr = row0+quad*4+r:
  //   K=gr>>5, quad'=((row0&16)+quad*4)>>3, j=(quad&1)*4 + r -> one 8B store/nb.
  const int K = row0 >> 5;
  const int quadp = ((row0 & 16) + quad * 4) >> 3;
  const int jlo = (quad & 1) * 4;
  const int lanep = quadp * 16 + m;
#pragma unroll
  for (int nb = 0; nb < 8; nb++) {
    bf16x4 v4 = {(__bf16)acc[nb][0], (__bf16)acc[nb][1],
                 (__bf16)acc[nb][2], (__bf16)acc[nb][3]};
    *(bf16x4*)(Vtb + ((size_t)K * 8 + nb) * 512 + lanep * 8 + jlo) = v4;
  }

  float a1v[8], a2v[8];
#pragma unroll
  for (int nb = 0; nb < 8; nb++) {
    a1v[nb] = a[nb * 16 + m];
    a2v[nb] = a[DIM + nb * 16 + m];
  }
  float tm_local = 0.f;  // biased-key max (biased t is positive)
#pragma unroll
  for (int r = 0; r < 4; r++) {
    const int gr = row0 + quad * 4 + r;
    float ps = 0.f, pt = 0.f;
#pragma unroll
    for (int nb = 0; nb < 8; nb++) {
      float e = acc[nb][r];
      ps += e * a1v[nb];
      pt += e * a2v[nb];
    }
    ps += __shfl_xor(ps, 1); ps += __shfl_xor(ps, 2);
    ps += __shfl_xor(ps, 4); ps += __shfl_xor(ps, 8);
    pt += __shfl_xor(pt, 1); pt += __shfl_xor(pt, 2);
    pt += __shfl_xor(pt, 4); pt += __shfl_xor(pt, 8);
    if (m == 0) {
      s[gr] = ps;
      t[gr] = pt;
      tm_local = fmaxf(tm_local, pt + 64.0f);
    }
  }
  if (m == 0) atomicMax(tmax, __float_as_uint(tm_local));
}

__device__ __forceinline__ unsigned pk4(int4 v) {
  return (unsigned)(v.x != 0) | ((unsigned)(v.y != 0) << 8) |
         ((unsigned)(v.z != 0) << 16) | ((unsigned)(v.w != 0) << 24);
}

// ---------------- kernel 2: masked softmax + PV, barrier-free, LDS-free -----
__global__ __launch_bounds__(256, 3) void k2_attn(const int* __restrict__ adj,
                                                  const __bf16* __restrict__ Vtb,
                                                  const float* __restrict__ s,
                                                  const float* __restrict__ t,
                                                  const unsigned* __restrict__ tmaxp,
                                                  float* __restrict__ part,
                                                  float* __restrict__ lpart) {
  const int tid = threadIdx.x;
  const int lane = tid & 63;
  const int w = tid >> 6;
  const int m = lane & 15;
  const int quad = lane >> 4;
  const int row0 = blockIdx.x * 128;
  const int base = row0 + w * 32;  // this wave: 32 rows, fully independent
  const int cs = blockIdx.y;
  const int col0 = cs * COLS_PER;
  const int rowA = base + m;
  const int rowB = base + 16 + m;

  const float Tmax = __uint_as_float(*tmaxp) - 64.0f;
  const float sA = s[rowA], sB = s[rowB];
  const float uA = sA + Tmax, uB = sB + Tmax;
  const float mA = fmaxf(uA, 0.01f * uA);  // per-row fixed softmax shift
  const float mB = fmaxf(uB, 0.01f * uB);

  f32x4 accA[8], accB[8];
#pragma unroll
  for (int nb = 0; nb < 8; nb++) {
    accA[nb] = (f32x4){0.f, 0.f, 0.f, 0.f};
    accB[nb] = (f32x4){0.f, 0.f, 0.f, 0.f};
  }
  float lA = 0.f, lB = 0.f;

  // coalesced adj loader: lane covers rows base+lr+{0,8,16,24}, 16B of cols
  const int lr = lane >> 3, lc = (lane & 7) * 4;
  const int* ab = adj + (size_t)(base + lr) * NN + col0 + lc;
  const float* tb = t + col0 + quad * 8;
  const __bf16* vb = Vtb + (size_t)cs * NCHUNK * 4096 + lane * 8;

  // fragment lane (quad,m) pulls its mask bytes from the loader lanes:
  //   srcLo holds row base+(m&7)+8p, cols quad*8..+3 ; srcHi the +4..+7 half.
  const int srcLo = (m & 7) * 8 + quad * 2;
  const int srcHi = srcLo + 1;
  const bool hiHalf = (m & 8) != 0;  // selects p-set 1/3 vs 0/2

  // 1-deep adj prefetch, NAMED register sets (r4: runtime-indexed = scratch)
  int4 aA0, aA1, aA2, aA3, aB0, aB1, aB2, aB3;

  auto fetchA = [&](int c) {
    const int* p = ab + c * BK;
    aA0 = *(const int4*)(p);
    aA1 = *(const int4*)(p + 8 * NN);
    aA2 = *(const int4*)(p + 16 * NN);
    aA3 = *(const int4*)(p + 24 * NN);
  };
  auto fetchB = [&](int c) {
    const int* p = ab + c * BK;
    aB0 = *(const int4*)(p);
    aB1 = *(const int4*)(p + 8 * NN);
    aB2 = *(const int4*)(p + 16 * NN);
    aB3 = *(const int4*)(p + 24 * NN);
  };

  // register-crossbar transpose: coalesced pk words -> fragment masks
  auto masks = [&](unsigned p0, unsigned p1, unsigned p2, unsigned p3,
                   unsigned long long& avA, unsigned long long& avB) {
    unsigned a0lo = (unsigned)__shfl((int)p0, srcLo);
    unsigned a1lo = (unsigned)__shfl((int)p1, srcLo);
    unsigned a0hi = (unsigned)__shfl((int)p0, srcHi);
    unsigned a1hi = (unsigned)__shfl((int)p1, srcHi);
    unsigned b0lo = (unsigned)__shfl((int)p2, srcLo);
    unsigned b1lo = (unsigned)__shfl((int)p3, srcLo);
    unsigned b0hi = (unsigned)__shfl((int)p2, srcHi);
    unsigned b1hi = (unsigned)__shfl((int)p3, srcHi);
    unsigned alo = hiHalf ? a1lo : a0lo;
    unsigned ahi = hiHalf ? a1hi : a0hi;
    unsigned blo = hiHalf ? b1lo : b0lo;
    unsigned bhi = hiHalf ? b1hi : b0hi;
    avA = (unsigned long long)alo | ((unsigned long long)ahi << 32);
    avB = (unsigned long long)blo | ((unsigned long long)bhi << 32);
  };

  auto compute = [&](unsigned long long avA, unsigned long long avB, int c) {
    float4 ct0 = *(const float4*)(tb + c * BK);
    float4 ct1 = *(const float4*)(tb + c * BK + 4);
    const __bf16* vc = vb + (size_t)c * 4096;
    bf16x8 bv[8];
#pragma unroll
    for (int nb = 0; nb < 8; nb++) bv[nb] = *(const bf16x8*)(vc + nb * 512);

    bf16x8 pA, pB;
#define PEL(frag, jj, tv, av, ss, mm, ll)                               \
    {                                                                   \
      float v = (ss) + (tv);                                            \
      float lv = fmaxf(v, 0.01f * v);                                   \
      float e = (((av) >> (8 * (jj))) & 1) ? __expf(lv - (mm)) : 0.f;   \
      (ll) += e;                                                        \
      frag[jj] = (__bf16)e;                                             \
    }
    PEL(pA, 0, ct0.x, avA, sA, mA, lA)
    PEL(pA, 1, ct0.y, avA, sA, mA, lA)
    PEL(pA, 2, ct0.z, avA, sA, mA, lA)
    PEL(pA, 3, ct0.w, avA, sA, mA, lA)
    PEL(pA, 4, ct1.x, avA, sA, mA, lA)
    PEL(pA, 5, ct1.y, avA, sA, mA, lA)
    PEL(pA, 6, ct1.z, avA, sA, mA, lA)
    PEL(pA, 7, ct1.w, avA, sA, mA, lA)
    PEL(pB, 0, ct0.x, avB, sB, mB, lB)
    PEL(pB, 1, ct0.y, avB, sB, mB, lB)
    PEL(pB, 2, ct0.z, avB, sB, mB, lB)
    PEL(pB, 3, ct0.w, avB, sB, mB, lB)
    PEL(pB, 4, ct1.x, avB, sB, mB, lB)
    PEL(pB, 5, ct1.y, avB, sB, mB, lB)
    PEL(pB, 6, ct1.z, avB, sB, mB, lB)
    PEL(pB, 7, ct1.w, avB, sB, mB, lB)
#undef PEL

#pragma unroll
    for (int nb = 0; nb < 8; nb++) {
      accA[nb] = __builtin_amdgcn_mfma_f32_16x16x32_bf16(pA, bv[nb], accA[nb], 0, 0, 0);
      accB[nb] = __builtin_amdgcn_mfma_f32_16x16x32_bf16(pB, bv[nb], accB[nb], 0, 0, 0);
    }
  };

  unsigned long long avA, avB;
  fetchA(0);
  for (int c = 0; c < NCHUNK; c += 2) {
    fetchB(c + 1);                     // prefetch next chunk's adj
    masks(pk4(aA0), pk4(aA1), pk4(aA2), pk4(aA3), avA, avB);  // waits on aA
    compute(avA, avB, c);
    if (c + 2 < NCHUNK) fetchA(c + 2);
    masks(pk4(aB0), pk4(aB1), pk4(aB2), pk4(aB3), avA, avB);
    compute(avA, avB, c + 1);
  }

  // row-sum partials: lanes {m, m+16, m+32, m+48} hold same row
  lA += __shfl_xor(lA, 16); lA += __shfl_xor(lA, 32);
  lB += __shfl_xor(lB, 16); lB += __shfl_xor(lB, 32);
  if (quad == 0) {
    lpart[(size_t)cs * NN + rowA] = lA;
    lpart[(size_t)cs * NN + rowB] = lB;
  }

  // C/D layout: row = quad*4 + r, col = nb*16 + m. Plain stores.
  float* po = part + ((size_t)cs * NN + base) * DIM;
#pragma unroll
  for (int nb = 0; nb < 8; nb++) {
#pragma unroll
    for (int r = 0; r < 4; r++) {
      po[(size_t)(quad * 4 + r) * DIM + nb * 16 + m] = accA[nb][r];
      po[(size_t)(16 + quad * 4 + r) * DIM + nb * 16 + m] = accB[nb][r];
    }
  }
}

// ---------------- kernel 3: reduce partials + normalize + relu ---------------
__global__ __launch_bounds__(256) void k3_fin(const float* __restrict__ part,
                                              const float* __restrict__ lpart,
                                              float* __restrict__ out) {
  __shared__ float linv_s[8];
  const int r0 = blockIdx.x * 8;  // 8 rows per block, 1536 blocks
  if (threadIdx.x < 8) {
    float l = 0.f;
#pragma unroll
    for (int cs = 0; cs < CSPLIT; cs++) l += lpart[(size_t)cs * NN + r0 + threadIdx.x];
    linv_s[threadIdx.x] = 1.0f / l;
  }
  __syncthreads();
  const int idx = blockIdx.x * 256 + threadIdx.x;  // float4 index over NN*DIM/4
  const float4* p4 = (const float4*)part;
  float4 acc = p4[idx];
#pragma unroll
  for (int cs = 1; cs < CSPLIT; cs++) {
    float4 v = p4[(size_t)cs * (NN * DIM / 4) + idx];
    acc.x += v.x; acc.y += v.y; acc.z += v.z; acc.w += v.w;
  }
  const float li = linv_s[threadIdx.x >> 5];
  float4 o;
  o.x = fmaxf(acc.x * li, 0.f);
  o.y = fmaxf(acc.y * li, 0.f);
  o.z = fmaxf(acc.z * li, 0.f);
  o.w = fmaxf(acc.w * li, 0.f);
  ((float4*)out)[idx] = o;
}

extern "C" void kernel_launch(void* const* d_in, const int* in_sizes, int n_in,
                              void* d_out, int out_size, void* d_ws, size_t ws_size,
                              hipStream_t stream) {
  (void)in_sizes; (void)n_in; (void)out_size; (void)ws_size;
  const float* emb = (const float*)d_in[0];
  const int* adj = (const int*)d_in[1];
  const float* W = (const float*)d_in[2];
  const float* a = (const float*)d_in[3];
  float* out = (float*)d_out;

  char* ws = (char*)d_ws;
  __bf16* Vtb = (__bf16*)ws;                      // 3,145,728 B (fragment layout)
  float* s = (float*)(ws + 3145728);              // 49,152 B
  float* t = (float*)(ws + 3194880);              // 49,152 B
  float* lpart = (float*)(ws + 3244032);          // 8*12288*4 = 393,216 B
  unsigned* tmax = (unsigned*)(ws + 3637248);     // 256 B
  float* part = (float*)(ws + 3637504);           // 8*12288*128*4 = 50,331,648 B

  hipMemsetAsync(tmax, 0, 4, stream);
  k1_gemm<<<NN / 16, 64, 0, stream>>>(emb, W, a, Vtb, s, t, tmax);
  dim3 g2(NN / 128, CSPLIT);
  k2_attn<<<g2, 256, 0, stream>>>(adj, Vtb, s, t, tmax, part, lpart);
  k3_fin<<<NN / 8, 256, 0, stream>>>(part, lpart, out);
}